// Round 1
// baseline (482.494 us; speedup 1.0000x reference)
//
#include <hip/hip_runtime.h>

// CausalSALayer: post-norm transformer decoder layer on gfx950.
// B=2, N=2048, D=1024, H=16, dk=64, FFN=4096. bf16 MFMA compute, f32 accum.

#define DEV __device__ __forceinline__

typedef __attribute__((ext_vector_type(4))) float f32x4;
typedef __attribute__((ext_vector_type(8))) short s16x8;

static constexpr int Bb   = 2;
static constexpr int NN   = 2048;
static constexpr int DM   = 1024;
static constexpr int HH   = 16;
static constexpr int DK   = 64;
static constexpr int FF   = 4096;
static constexpr int ROWS = Bb * NN;  // 4096

DEV unsigned short f2bf(float f) {
  unsigned u = __float_as_uint(f);
  u += 0x7fff + ((u >> 16) & 1);   // RNE
  return (unsigned short)(u >> 16);
}

// ---------------- cast f32 -> bf16 (vectorized) ----------------
__global__ __launch_bounds__(256) void k_cast(const float* __restrict__ in,
                                              ushort* __restrict__ out, int n4) {
  int i = blockIdx.x * 256 + threadIdx.x;
  if (i >= n4) return;
  float4 v = reinterpret_cast<const float4*>(in)[i];
  ushort4 o;
  o.x = f2bf(v.x); o.y = f2bf(v.y); o.z = f2bf(v.z); o.w = f2bf(v.w);
  reinterpret_cast<ushort4*>(out)[i] = o;
}

// ---------------- GEMM: C[M,N] = A[M,K](bf16) * Bt[N,K](bf16)^T ----------------
// EPI 0: C -> bf16 plain
// EPI 1: C + bias, gelu(tanh) -> bf16
// EPI 2: C + bias + resid(f32) -> f32
template <int EPI>
__global__ __launch_bounds__(256) void k_gemm_bt(
    const ushort* __restrict__ A, const ushort* __restrict__ Bt,
    const float* __restrict__ bias, const float* __restrict__ resid,
    ushort* __restrict__ Cb, float* __restrict__ Cf,
    int M, int N, int K) {
  __shared__ ushort As[128][40];   // 40-elem rows: 80B stride, 16B aligned, ~2-way banks
  __shared__ ushort Bs[128][40];

  const int t = threadIdx.x;
  const int bRow = blockIdx.y * 128, bCol = blockIdx.x * 128;
  const int lane = t & 63, wid = t >> 6;
  const int lr = lane & 15, lg = lane >> 4;
  const int wRow = (wid >> 1) * 64, wCol = (wid & 1) * 64;

  const f32x4 zero = {0.f, 0.f, 0.f, 0.f};
  f32x4 acc[4][4];
#pragma unroll
  for (int m = 0; m < 4; ++m)
#pragma unroll
    for (int n = 0; n < 4; ++n) acc[m][n] = zero;

  const int srow = t >> 2;        // 0..63
  const int sc8  = (t & 3) * 8;   // 0,8,16,24

  for (int kt = 0; kt < K; kt += 32) {
#pragma unroll
    for (int h = 0; h < 2; ++h) {
      int r = srow + h * 64;
      int4 av = *reinterpret_cast<const int4*>(A + (size_t)(bRow + r) * K + kt + sc8);
      *reinterpret_cast<int4*>(&As[r][sc8]) = av;
      int4 bv = *reinterpret_cast<const int4*>(Bt + (size_t)(bCol + r) * K + kt + sc8);
      *reinterpret_cast<int4*>(&Bs[r][sc8]) = bv;
    }
    __syncthreads();

    s16x8 af[4], bf[4];
#pragma unroll
    for (int m = 0; m < 4; ++m)
      af[m] = *reinterpret_cast<const s16x8*>(&As[wRow + m * 16 + lr][lg * 8]);
#pragma unroll
    for (int n = 0; n < 4; ++n)
      bf[n] = *reinterpret_cast<const s16x8*>(&Bs[wCol + n * 16 + lr][lg * 8]);
#pragma unroll
    for (int m = 0; m < 4; ++m)
#pragma unroll
      for (int n = 0; n < 4; ++n)
        acc[m][n] = __builtin_amdgcn_mfma_f32_16x16x32_bf16(af[m], bf[n], acc[m][n], 0, 0, 0);
    __syncthreads();
  }

#pragma unroll
  for (int m = 0; m < 4; ++m) {
    int gr = bRow + wRow + m * 16 + lg * 4;
#pragma unroll
    for (int n = 0; n < 4; ++n) {
      int gc = bCol + wCol + n * 16 + lr;
      float bv = (EPI == 1 || EPI == 2) ? bias[gc] : 0.0f;
#pragma unroll
      for (int r = 0; r < 4; ++r) {
        size_t idx = (size_t)(gr + r) * N + gc;
        float v = acc[m][n][r] + bv;
        if (EPI == 2) {
          Cf[idx] = v + resid[idx];
        } else if (EPI == 1) {
          float g = 0.5f * v * (1.0f + tanhf(0.7978845608028654f * (v + 0.044715f * v * v * v)));
          Cb[idx] = f2bf(g);
        } else {
          Cb[idx] = f2bf(v);
        }
      }
    }
  }
}

// ---------------- LayerNorm over D=1024 rows ----------------
template <int WB>
__global__ __launch_bounds__(256) void k_ln(const float* __restrict__ in,
                                            const float* __restrict__ g,
                                            const float* __restrict__ bta,
                                            float* __restrict__ outf,
                                            ushort* __restrict__ outb) {
  const int row = blockIdx.x;
  const int t = threadIdx.x;
  float4 v = reinterpret_cast<const float4*>(in + (size_t)row * DM)[t];
  float s1 = v.x + v.y + v.z + v.w;
  float s2 = v.x * v.x + v.y * v.y + v.z * v.z + v.w * v.w;
#pragma unroll
  for (int m = 32; m; m >>= 1) {
    s1 += __shfl_xor(s1, m, 64);
    s2 += __shfl_xor(s2, m, 64);
  }
  __shared__ float red[2][4];
  if ((t & 63) == 0) { red[0][t >> 6] = s1; red[1][t >> 6] = s2; }
  __syncthreads();
  s1 = red[0][0] + red[0][1] + red[0][2] + red[0][3];
  s2 = red[1][0] + red[1][1] + red[1][2] + red[1][3];
  const float mu = s1 * (1.0f / DM);
  const float var = s2 * (1.0f / DM) - mu * mu;
  const float rstd = rsqrtf(var + 1e-5f);
  float4 gv = reinterpret_cast<const float4*>(g)[t];
  float4 bv = reinterpret_cast<const float4*>(bta)[t];
  float4 o;
  o.x = (v.x - mu) * rstd * gv.x + bv.x;
  o.y = (v.y - mu) * rstd * gv.y + bv.y;
  o.z = (v.z - mu) * rstd * gv.z + bv.z;
  o.w = (v.w - mu) * rstd * gv.w + bv.w;
  reinterpret_cast<float4*>(outf + (size_t)row * DM)[t] = o;
  if (WB) {
    ushort4 ob;
    ob.x = f2bf(o.x); ob.y = f2bf(o.y); ob.z = f2bf(o.z); ob.w = f2bf(o.w);
    reinterpret_cast<ushort4*>(outb + (size_t)row * DM)[t] = ob;
  }
}

// ---------------- causal flash attention ----------------
// grid: (N/64, B*H). 4 waves/block; wave w handles 16 queries. 32-key tiles.
__global__ __launch_bounds__(256) void k_attn(const ushort* __restrict__ Q,
                                              const ushort* __restrict__ Kb,
                                              const ushort* __restrict__ Vb,
                                              ushort* __restrict__ O) {
  __shared__ ushort Ks[32][72];        // K tile, 144B rows (16B aligned)
  __shared__ ushort Vt[64][40];        // V^T tile: [d][key], 80B rows
  __shared__ ushort Pl[4][16][40];     // per-wave P tile [q][key]

  const int t = threadIdx.x;
  const int qb = blockIdx.x;
  const int bh = blockIdx.y;
  const int b = bh >> 4, h = bh & 15;
  const int lane = t & 63, wid = t >> 6;
  const int lr = lane & 15, lg = lane >> 4;
  const int q0 = qb * 64 + wid * 16;

  const size_t base = ((size_t)b * NN) * DM + h * DK;

  s16x8 qf[2];
#pragma unroll
  for (int c = 0; c < 2; ++c)
    qf[c] = *reinterpret_cast<const s16x8*>(Q + base + (size_t)(q0 + lr) * DM + c * 32 + lg * 8);

  float mrun[4], lrun[4];
  const f32x4 zero = {0.f, 0.f, 0.f, 0.f};
  f32x4 acc[4];
#pragma unroll
  for (int r = 0; r < 4; ++r) { mrun[r] = -1e30f; lrun[r] = 0.f; }
#pragma unroll
  for (int cd = 0; cd < 4; ++cd) acc[cd] = zero;

  const int skey = t >> 3;             // K staging: 32 keys x 64 d
  const int sc8  = (t & 7) * 8;
  const int vkey = t & 31;             // V staging: transposed write
  const int vd8  = (t >> 5) * 8;

  const int nkb = 2 * qb + 2;
  for (int kb = 0; kb < nkb; ++kb) {
    const int kk = kb * 32;
    {
      int4 kv = *reinterpret_cast<const int4*>(Kb + base + (size_t)(kk + skey) * DM + sc8);
      *reinterpret_cast<int4*>(&Ks[skey][sc8]) = kv;
      int4 vv = *reinterpret_cast<const int4*>(Vb + base + (size_t)(kk + vkey) * DM + vd8);
      ushort vs[8];
      *reinterpret_cast<int4*>(vs) = vv;
#pragma unroll
      for (int j = 0; j < 8; ++j) Vt[vd8 + j][vkey] = vs[j];
    }
    __syncthreads();

    // S = Q K^T (16q x 32k)
    f32x4 s[2] = {zero, zero};
#pragma unroll
    for (int ck = 0; ck < 2; ++ck)
#pragma unroll
      for (int c = 0; c < 2; ++c) {
        s16x8 kf = *reinterpret_cast<const s16x8*>(&Ks[ck * 16 + lr][c * 32 + lg * 8]);
        s[ck] = __builtin_amdgcn_mfma_f32_16x16x32_bf16(qf[c], kf, s[ck], 0, 0, 0);
      }

    float p[2][4], rm[4];
#pragma unroll
    for (int r = 0; r < 4; ++r) {
      int qi = q0 + lg * 4 + r;
      float a0 = (kk + lr      <= qi) ? s[0][r] * 0.125f : -1e30f;
      float a1 = (kk + 16 + lr <= qi) ? s[1][r] * 0.125f : -1e30f;
      p[0][r] = a0; p[1][r] = a1;
      rm[r] = fmaxf(a0, a1);
    }
#pragma unroll
    for (int r = 0; r < 4; ++r)
#pragma unroll
      for (int m = 1; m < 16; m <<= 1) rm[r] = fmaxf(rm[r], __shfl_xor(rm[r], m, 64));

    float alpha[4], rs[4];
#pragma unroll
    for (int r = 0; r < 4; ++r) {
      float mn = fmaxf(mrun[r], rm[r]);
      alpha[r] = __expf(mrun[r] - mn);
      mrun[r] = mn;
      p[0][r] = __expf(p[0][r] - mn);
      p[1][r] = __expf(p[1][r] - mn);
      rs[r] = p[0][r] + p[1][r];
    }
#pragma unroll
    for (int r = 0; r < 4; ++r)
#pragma unroll
      for (int m = 1; m < 16; m <<= 1) rs[r] += __shfl_xor(rs[r], m, 64);
#pragma unroll
    for (int r = 0; r < 4; ++r) lrun[r] = lrun[r] * alpha[r] + rs[r];
#pragma unroll
    for (int cd = 0; cd < 4; ++cd)
#pragma unroll
      for (int r = 0; r < 4; ++r) acc[cd][r] *= alpha[r];

#pragma unroll
    for (int ck = 0; ck < 2; ++ck)
#pragma unroll
      for (int r = 0; r < 4; ++r)
        Pl[wid][lg * 4 + r][ck * 16 + lr] = f2bf(p[ck][r]);
    asm volatile("s_waitcnt lgkmcnt(0)" ::: "memory");

    // O += P V   (P: 16q x 32k, V: 32k x 64d)
    s16x8 pf = *reinterpret_cast<const s16x8*>(&Pl[wid][lr][lg * 8]);
#pragma unroll
    for (int cd = 0; cd < 4; ++cd) {
      s16x8 vf = *reinterpret_cast<const s16x8*>(&Vt[cd * 16 + lr][lg * 8]);
      acc[cd] = __builtin_amdgcn_mfma_f32_16x16x32_bf16(pf, vf, acc[cd], 0, 0, 0);
    }
    __syncthreads();
  }

#pragma unroll
  for (int cd = 0; cd < 4; ++cd)
#pragma unroll
    for (int r = 0; r < 4; ++r) {
      float o = acc[cd][r] / lrun[r];
      O[base + (size_t)(q0 + lg * 4 + r) * DM + cd * 16 + lr] = f2bf(o);
    }
}

// ---------------- launch ----------------
extern "C" void kernel_launch(void* const* d_in, const int* in_sizes, int n_in,
                              void* d_out, int out_size, void* d_ws, size_t ws_size,
                              hipStream_t stream) {
  const float* tgt = (const float*)d_in[0];
  const float* Wq  = (const float*)d_in[3];
  const float* Wk  = (const float*)d_in[4];
  const float* Wv  = (const float*)d_in[5];
  const float* Wo  = (const float*)d_in[6];
  const float* bo  = (const float*)d_in[7];
  const float* W1  = (const float*)d_in[8];
  const float* b1  = (const float*)d_in[9];
  const float* W2  = (const float*)d_in[10];
  const float* b2  = (const float*)d_in[11];
  const float* g1  = (const float*)d_in[12];
  const float* be1 = (const float*)d_in[13];
  const float* g2  = (const float*)d_in[14];
  const float* be2 = (const float*)d_in[15];

  char* ws = (char*)d_ws;
  size_t off = 0;
  auto alloc = [&](size_t bytes) {
    void* p = ws + off;
    off += (bytes + 255) & ~(size_t)255;
    return p;
  };
  ushort* xb   = (ushort*)alloc((size_t)ROWS * DM * 2);   // 8 MB
  ushort* wqb  = (ushort*)alloc((size_t)DM * DM * 2);
  ushort* wkb  = (ushort*)alloc((size_t)DM * DM * 2);
  ushort* wvb  = (ushort*)alloc((size_t)DM * DM * 2);
  ushort* wob  = (ushort*)alloc((size_t)DM * DM * 2);
  ushort* w1b  = (ushort*)alloc((size_t)FF * DM * 2);
  ushort* w2b  = (ushort*)alloc((size_t)DM * FF * 2);
  ushort* qbuf = (ushort*)alloc((size_t)ROWS * DM * 2);
  ushort* kbuf = (ushort*)alloc((size_t)ROWS * DM * 2);
  ushort* vbuf = (ushort*)alloc((size_t)ROWS * DM * 2);
  ushort* atnb = (ushort*)alloc((size_t)ROWS * DM * 2);
  float*  h1   = (float*)alloc((size_t)ROWS * DM * 4);    // reused as z
  float*  x1f  = (float*)alloc((size_t)ROWS * DM * 4);
  ushort* x1b  = (ushort*)alloc((size_t)ROWS * DM * 2);
  ushort* t1b  = (ushort*)alloc((size_t)ROWS * FF * 2);   // 32 MB
  (void)ws_size; (void)in_sizes; (void)n_in; (void)out_size;

  auto cast = [&](const float* src, ushort* dst, size_t n) {
    int n4 = (int)(n / 4);
    k_cast<<<dim3((n4 + 255) / 256), 256, 0, stream>>>(src, dst, n4);
  };
  cast(tgt, xb, (size_t)ROWS * DM);
  cast(Wq, wqb, (size_t)DM * DM);
  cast(Wk, wkb, (size_t)DM * DM);
  cast(Wv, wvb, (size_t)DM * DM);
  cast(Wo, wob, (size_t)DM * DM);
  cast(W1, w1b, (size_t)FF * DM);
  cast(W2, w2b, (size_t)DM * FF);

  dim3 blk(256);
  // QKV projections (no bias)
  k_gemm_bt<0><<<dim3(DM / 128, ROWS / 128), blk, 0, stream>>>(
      xb, wqb, nullptr, nullptr, qbuf, nullptr, ROWS, DM, DM);
  k_gemm_bt<0><<<dim3(DM / 128, ROWS / 128), blk, 0, stream>>>(
      xb, wkb, nullptr, nullptr, kbuf, nullptr, ROWS, DM, DM);
  k_gemm_bt<0><<<dim3(DM / 128, ROWS / 128), blk, 0, stream>>>(
      xb, wvb, nullptr, nullptr, vbuf, nullptr, ROWS, DM, DM);

  k_attn<<<dim3(NN / 64, Bb * HH), blk, 0, stream>>>(qbuf, kbuf, vbuf, atnb);

  // O-projection + bo + residual(tgt) -> f32 h1
  k_gemm_bt<2><<<dim3(DM / 128, ROWS / 128), blk, 0, stream>>>(
      atnb, wob, bo, tgt, nullptr, h1, ROWS, DM, DM);
  k_ln<1><<<dim3(ROWS), blk, 0, stream>>>(h1, g1, be1, x1f, x1b);

  // FFN
  k_gemm_bt<1><<<dim3(FF / 128, ROWS / 128), blk, 0, stream>>>(
      x1b, w1b, b1, nullptr, t1b, nullptr, ROWS, FF, DM);
  float* z = h1;
  k_gemm_bt<2><<<dim3(DM / 128, ROWS / 128), blk, 0, stream>>>(
      t1b, w2b, b2, x1f, nullptr, z, ROWS, DM, FF);
  k_ln<0><<<dim3(ROWS), blk, 0, stream>>>(z, g2, be2, (float*)d_out, nullptr);
}

// Round 2
// 392.513 us; speedup vs baseline: 1.2292x; 1.2292x over previous
//
#include <hip/hip_runtime.h>

// CausalSALayer: post-norm transformer decoder layer on gfx950.
// B=2, N=2048, D=1024, H=16, dk=64, FFN=4096. bf16 MFMA compute, f32 accum.

#define DEV __device__ __forceinline__

typedef __attribute__((ext_vector_type(4)))  float f32x4;
typedef __attribute__((ext_vector_type(16))) float f32x16;
typedef __attribute__((ext_vector_type(8)))  short s16x8;

static constexpr int Bb   = 2;
static constexpr int NN   = 2048;
static constexpr int DM   = 1024;
static constexpr int HH   = 16;
static constexpr int DK   = 64;
static constexpr int FF   = 4096;
static constexpr int ROWS = Bb * NN;  // 4096

#define AS1(p) ((const __attribute__((address_space(1))) void*)(p))
#define AS3(p) ((__attribute__((address_space(3))) void*)(p))

DEV unsigned short f2bf(float f) {
  unsigned u = __float_as_uint(f);
  u += 0x7fff + ((u >> 16) & 1);   // RNE
  return (unsigned short)(u >> 16);
}
DEV unsigned pack2bf(float lo, float hi) {
  return (unsigned)f2bf(lo) | ((unsigned)f2bf(hi) << 16);
}

// ---------------- cast f32 -> bf16 (vectorized) ----------------
__global__ __launch_bounds__(256) void k_cast(const float* __restrict__ in,
                                              ushort* __restrict__ out, int n4) {
  int i = blockIdx.x * 256 + threadIdx.x;
  if (i >= n4) return;
  float4 v = reinterpret_cast<const float4*>(in)[i];
  ushort4 o;
  o.x = f2bf(v.x); o.y = f2bf(v.y); o.z = f2bf(v.z); o.w = f2bf(v.w);
  reinterpret_cast<ushort4*>(out)[i] = o;
}

// ---------------- GEMM (m97 structure): C[M,N] = A[M,K] * Bt[N,K]^T ----------------
// EPI 0: C -> bf16 plain ; EPI 1: C+bias, gelu -> bf16 ; EPI 2: C+bias+resid -> f32
template <int EPI>
__global__ __launch_bounds__(256) void k_gemm_bt(
    const ushort* __restrict__ A, const ushort* __restrict__ Bt,
    const float* __restrict__ bias, const float* __restrict__ resid,
    ushort* __restrict__ Cb, float* __restrict__ Cf,
    int M, int N, int K) {
  __shared__ ushort As[128][32];   // linear: global_load_lds dest must be contiguous
  __shared__ ushort Bs[128][32];

  const int t = threadIdx.x;
  const int bRow = blockIdx.y * 128, bCol = blockIdx.x * 128;
  const int lane = t & 63, w = t >> 6;
  const int lr = lane & 15, lg = lane >> 4;
  const int wRow = (w >> 1) * 64, wCol = (w & 1) * 64;

  const f32x4 zero = {0.f, 0.f, 0.f, 0.f};
  f32x4 acc[4][4];
#pragma unroll
  for (int m = 0; m < 4; ++m)
#pragma unroll
    for (int n = 0; n < 4; ++n) acc[m][n] = zero;

  const int lrow = lane >> 2;        // 0..15 within a 1KB wave store
  const int lc8  = (lane & 3) * 8;   // k-offset

  for (int kt = 0; kt < K; kt += 32) {
#pragma unroll
    for (int i = 0; i < 2; ++i) {
      int r = w * 32 + i * 16 + lrow;
      __builtin_amdgcn_global_load_lds(
          AS1(A + (size_t)(bRow + r) * K + kt + lc8),
          AS3(&As[w * 32 + i * 16][0]), 16, 0, 0);
      __builtin_amdgcn_global_load_lds(
          AS1(Bt + (size_t)(bCol + r) * K + kt + lc8),
          AS3(&Bs[w * 32 + i * 16][0]), 16, 0, 0);
    }
    __syncthreads();

    s16x8 af[4], bfr[4];
#pragma unroll
    for (int m = 0; m < 4; ++m)
      af[m] = *reinterpret_cast<const s16x8*>(&As[wRow + m * 16 + lr][lg * 8]);
#pragma unroll
    for (int n = 0; n < 4; ++n)
      bfr[n] = *reinterpret_cast<const s16x8*>(&Bs[wCol + n * 16 + lr][lg * 8]);
#pragma unroll
    for (int m = 0; m < 4; ++m)
#pragma unroll
      for (int n = 0; n < 4; ++n)
        acc[m][n] = __builtin_amdgcn_mfma_f32_16x16x32_bf16(af[m], bfr[n], acc[m][n], 0, 0, 0);
    __syncthreads();
  }

#pragma unroll
  for (int m = 0; m < 4; ++m) {
    int gr = bRow + wRow + m * 16 + lg * 4;
#pragma unroll
    for (int n = 0; n < 4; ++n) {
      int gc = bCol + wCol + n * 16 + lr;
      float bv = (EPI == 1 || EPI == 2) ? bias[gc] : 0.0f;
#pragma unroll
      for (int r = 0; r < 4; ++r) {
        size_t idx = (size_t)(gr + r) * N + gc;
        float v = acc[m][n][r] + bv;
        if (EPI == 2) {
          Cf[idx] = v + resid[idx];
        } else if (EPI == 1) {
          float g = 0.5f * v * (1.0f + tanhf(0.7978845608028654f * (v + 0.044715f * v * v * v)));
          Cb[idx] = f2bf(g);
        } else {
          Cb[idx] = f2bf(v);
        }
      }
    }
  }
}

// ---------------- LayerNorm over D=1024 rows ----------------
template <int WB>
__global__ __launch_bounds__(256) void k_ln(const float* __restrict__ in,
                                            const float* __restrict__ g,
                                            const float* __restrict__ bta,
                                            float* __restrict__ outf,
                                            ushort* __restrict__ outb) {
  const int row = blockIdx.x;
  const int t = threadIdx.x;
  float4 v = reinterpret_cast<const float4*>(in + (size_t)row * DM)[t];
  float s1 = v.x + v.y + v.z + v.w;
  float s2 = v.x * v.x + v.y * v.y + v.z * v.z + v.w * v.w;
#pragma unroll
  for (int m = 32; m; m >>= 1) {
    s1 += __shfl_xor(s1, m, 64);
    s2 += __shfl_xor(s2, m, 64);
  }
  __shared__ float red[2][4];
  if ((t & 63) == 0) { red[0][t >> 6] = s1; red[1][t >> 6] = s2; }
  __syncthreads();
  s1 = red[0][0] + red[0][1] + red[0][2] + red[0][3];
  s2 = red[1][0] + red[1][1] + red[1][2] + red[1][3];
  const float mu = s1 * (1.0f / DM);
  const float var = s2 * (1.0f / DM) - mu * mu;
  const float rstd = rsqrtf(var + 1e-5f);
  float4 gv = reinterpret_cast<const float4*>(g)[t];
  float4 bv = reinterpret_cast<const float4*>(bta)[t];
  float4 o;
  o.x = (v.x - mu) * rstd * gv.x + bv.x;
  o.y = (v.y - mu) * rstd * gv.y + bv.y;
  o.z = (v.z - mu) * rstd * gv.z + bv.z;
  o.w = (v.w - mu) * rstd * gv.w + bv.w;
  reinterpret_cast<float4*>(outf + (size_t)row * DM)[t] = o;
  if (WB) {
    ushort4 ob;
    ob.x = f2bf(o.x); ob.y = f2bf(o.y); ob.z = f2bf(o.z); ob.w = f2bf(o.w);
    reinterpret_cast<ushort4*>(outb + (size_t)row * DM)[t] = ob;
  }
}

// ---------------- causal flash attention: swapped-operand 32x32 ----------------
// grid: (N/128, B*H), 256 threads (4 waves x 32 queries). KVBLK=64.
// S^T = mfma(K, Q)  -> lane holds P[k0..31] for q = lane&31 (lane-local softmax)
// O^T = mfma(V^T, P^T) -> rescale is lane-uniform
__global__ __launch_bounds__(256) void k_attn(const ushort* __restrict__ Q,
                                              const ushort* __restrict__ Kb,
                                              const ushort* __restrict__ Vb,
                                              ushort* __restrict__ O) {
  __shared__ ushort Ks[64 * 64];   // byte-addressed, XOR-swizzled rows of 128B
  __shared__ ushort Vt[64][72];    // V^T [d][key], +8 pad

  const int t = threadIdx.x;
  const int qi = (NN / 128 - 1) - (int)blockIdx.x;   // heavy blocks first
  const int bh = blockIdx.y;
  const int b = bh >> 4, h = bh & 15;
  const int lane = t & 63, wid = t >> 6;
  const int l31 = lane & 31, hi = lane >> 5;
  const int q_base = qi * 128;
  const int q0w = q_base + wid * 32;
  const size_t base = ((size_t)b * NN) * DM + h * DK;

  char* KsB = (char*)Ks;

  // Q fragments: B-operand of mfma(K,Q): lane holds q=lane&31, d = c*16 + hi*8 + j
  s16x8 qf[4];
#pragma unroll
  for (int c = 0; c < 4; ++c)
    qf[c] = *reinterpret_cast<const s16x8*>(Q + base + (size_t)(q0w + l31) * DM + c * 16 + hi * 8);

  float mrun = -1e30f, lrun = 0.f;
  f32x16 accO[2];
#pragma unroll
  for (int dt = 0; dt < 2; ++dt)
#pragma unroll
    for (int r = 0; r < 16; ++r) accO[dt][r] = 0.f;

  const int srow = t >> 2;       // 0..63: K row / V key
  const int sc4  = t & 3;

  const int nkt = 2 * qi + 2;
  for (int kt = 0; kt < nkt; ++kt) {
    const int kk = kt * 64;
    // ---- stage K (swizzled rows) + V^T ----
#pragma unroll
    for (int hh = 0; hh < 2; ++hh) {
      int co = sc4 * 16 + hh * 64;   // byte col within 128B row
      int4 kv = *reinterpret_cast<const int4*>(Kb + base + (size_t)(kk + srow) * DM + (co >> 1));
      *reinterpret_cast<int4*>(KsB + srow * 128 + (co ^ ((srow & 7) << 4))) = kv;
      int d0 = sc4 * 8 + hh * 32;
      int4 vv = *reinterpret_cast<const int4*>(Vb + base + (size_t)(kk + srow) * DM + d0);
      ushort vs[8];
      *reinterpret_cast<int4*>(vs) = vv;
#pragma unroll
      for (int j = 0; j < 8; ++j) Vt[d0 + j][srow] = vs[j];
    }
    __syncthreads();

    if (kk <= q0w + 31) {   // wave-uniform
      // ---- S^T = K Q^T : two 32x32 tiles over 64 keys ----
      f32x16 st[2];
#pragma unroll
      for (int sub = 0; sub < 2; ++sub) {
#pragma unroll
        for (int r = 0; r < 16; ++r) st[sub][r] = 0.f;
        const int row = sub * 32 + l31;
        const int swz = (row & 7) << 4;
#pragma unroll
        for (int c = 0; c < 4; ++c) {
          s16x8 kf = *reinterpret_cast<const s16x8*>(KsB + row * 128 + ((c * 32 + hi * 16) ^ swz));
          st[sub] = __builtin_amdgcn_mfma_f32_32x32x16_bf16(kf, qf[c], st[sub], 0, 0, 0);
        }
      }

      // ---- mask + lane-local online softmax (q = q0w + l31) ----
      const int q = q0w + l31;
      const bool needmask = (kk + 63 > q0w);
      float p[32];
      float rm = -1e30f;
#pragma unroll
      for (int sub = 0; sub < 2; ++sub)
#pragma unroll
        for (int r = 0; r < 16; ++r) {
          int kl = sub * 32 + (r & 3) + 8 * (r >> 2) + 4 * hi;
          float v = st[sub][r] * 0.125f;
          if (needmask && (kk + kl > q)) v = -1e30f;
          p[sub * 16 + r] = v;
          rm = fmaxf(rm, v);
        }
      rm = fmaxf(rm, __shfl_xor(rm, 32, 64));
      const float mn = fmaxf(mrun, rm);
      const float alpha = __expf(mrun - mn);
      mrun = mn;
      float rs = 0.f;
#pragma unroll
      for (int i = 0; i < 32; ++i) { p[i] = __expf(p[i] - mn); rs += p[i]; }
      rs += __shfl_xor(rs, 32, 64);
      lrun = lrun * alpha + rs;
#pragma unroll
      for (int dt = 0; dt < 2; ++dt) accO[dt] *= alpha;

      // ---- pack P^T into PV B-operand frags (pair-pack + permlane32_swap) ----
      s16x8 pf[4];
#pragma unroll
      for (int sub = 0; sub < 2; ++sub)
#pragma unroll
        for (int half = 0; half < 2; ++half) {
          const float* pp = &p[sub * 16 + half * 8];
          unsigned X0 = pack2bf(pp[0], pp[1]);
          unsigned X1 = pack2bf(pp[2], pp[3]);
          unsigned Y0 = pack2bf(pp[4], pp[5]);
          unsigned Y1 = pack2bf(pp[6], pp[7]);
          asm volatile("v_permlane32_swap_b32 %0, %1" : "+v"(X0), "+v"(Y0));
          asm volatile("v_permlane32_swap_b32 %0, %1" : "+v"(X1), "+v"(Y1));
          union { unsigned u[4]; s16x8 v; } uu;
          uu.u[0] = X0; uu.u[1] = X1; uu.u[2] = Y0; uu.u[3] = Y1;
          pf[sub * 2 + half] = uu.v;
        }

      // ---- O^T += V^T P^T ----
#pragma unroll
      for (int dt = 0; dt < 2; ++dt) {
        const int d = dt * 32 + l31;
#pragma unroll
        for (int kc = 0; kc < 4; ++kc) {
          s16x8 vf = *reinterpret_cast<const s16x8*>(&Vt[d][kc * 16 + hi * 8]);
          accO[dt] = __builtin_amdgcn_mfma_f32_32x32x16_bf16(vf, pf[kc], accO[dt], 0, 0, 0);
        }
      }
    }
    __syncthreads();
  }

  // ---- epilogue: O[q][d] = accO^T / lrun ----
  const int q = q0w + l31;
  const float inv = 1.0f / lrun;
#pragma unroll
  for (int dt = 0; dt < 2; ++dt)
#pragma unroll
    for (int rg = 0; rg < 4; ++rg) {
      int d0 = 8 * rg + 4 * hi + 32 * dt;
      ushort4 ov;
      ov.x = f2bf(accO[dt][rg * 4 + 0] * inv);
      ov.y = f2bf(accO[dt][rg * 4 + 1] * inv);
      ov.z = f2bf(accO[dt][rg * 4 + 2] * inv);
      ov.w = f2bf(accO[dt][rg * 4 + 3] * inv);
      *reinterpret_cast<ushort4*>(O + base + (size_t)q * DM + d0) = ov;
    }
}

// ---------------- launch ----------------
extern "C" void kernel_launch(void* const* d_in, const int* in_sizes, int n_in,
                              void* d_out, int out_size, void* d_ws, size_t ws_size,
                              hipStream_t stream) {
  const float* tgt = (const float*)d_in[0];
  const float* Wq  = (const float*)d_in[3];
  const float* Wk  = (const float*)d_in[4];
  const float* Wv  = (const float*)d_in[5];
  const float* Wo  = (const float*)d_in[6];
  const float* bo  = (const float*)d_in[7];
  const float* W1  = (const float*)d_in[8];
  const float* b1  = (const float*)d_in[9];
  const float* W2  = (const float*)d_in[10];
  const float* b2  = (const float*)d_in[11];
  const float* g1  = (const float*)d_in[12];
  const float* be1 = (const float*)d_in[13];
  const float* g2  = (const float*)d_in[14];
  const float* be2 = (const float*)d_in[15];

  char* ws = (char*)d_ws;
  size_t off = 0;
  auto alloc = [&](size_t bytes) {
    void* p = ws + off;
    off += (bytes + 255) & ~(size_t)255;
    return p;
  };
  ushort* xb   = (ushort*)alloc((size_t)ROWS * DM * 2);
  ushort* wqb  = (ushort*)alloc((size_t)DM * DM * 2);
  ushort* wkb  = (ushort*)alloc((size_t)DM * DM * 2);
  ushort* wvb  = (ushort*)alloc((size_t)DM * DM * 2);
  ushort* wob  = (ushort*)alloc((size_t)DM * DM * 2);
  ushort* w1b  = (ushort*)alloc((size_t)FF * DM * 2);
  ushort* w2b  = (ushort*)alloc((size_t)DM * FF * 2);
  ushort* qbuf = (ushort*)alloc((size_t)ROWS * DM * 2);
  ushort* kbuf = (ushort*)alloc((size_t)ROWS * DM * 2);
  ushort* vbuf = (ushort*)alloc((size_t)ROWS * DM * 2);
  ushort* atnb = (ushort*)alloc((size_t)ROWS * DM * 2);
  float*  h1   = (float*)alloc((size_t)ROWS * DM * 4);    // reused as z
  float*  x1f  = (float*)alloc((size_t)ROWS * DM * 4);
  ushort* x1b  = (ushort*)alloc((size_t)ROWS * DM * 2);
  ushort* t1b  = (ushort*)alloc((size_t)ROWS * FF * 2);
  (void)ws_size; (void)in_sizes; (void)n_in; (void)out_size;

  auto cast = [&](const float* src, ushort* dst, size_t n) {
    int n4 = (int)(n / 4);
    k_cast<<<dim3((n4 + 255) / 256), 256, 0, stream>>>(src, dst, n4);
  };
  cast(tgt, xb, (size_t)ROWS * DM);
  cast(Wq, wqb, (size_t)DM * DM);
  cast(Wk, wkb, (size_t)DM * DM);
  cast(Wv, wvb, (size_t)DM * DM);
  cast(Wo, wob, (size_t)DM * DM);
  cast(W1, w1b, (size_t)FF * DM);
  cast(W2, w2b, (size_t)DM * FF);

  dim3 blk(256);
  k_gemm_bt<0><<<dim3(DM / 128, ROWS / 128), blk, 0, stream>>>(
      xb, wqb, nullptr, nullptr, qbuf, nullptr, ROWS, DM, DM);
  k_gemm_bt<0><<<dim3(DM / 128, ROWS / 128), blk, 0, stream>>>(
      xb, wkb, nullptr, nullptr, kbuf, nullptr, ROWS, DM, DM);
  k_gemm_bt<0><<<dim3(DM / 128, ROWS / 128), blk, 0, stream>>>(
      xb, wvb, nullptr, nullptr, vbuf, nullptr, ROWS, DM, DM);

  k_attn<<<dim3(NN / 128, Bb * HH), blk, 0, stream>>>(qbuf, kbuf, vbuf, atnb);

  k_gemm_bt<2><<<dim3(DM / 128, ROWS / 128), blk, 0, stream>>>(
      atnb, wob, bo, tgt, nullptr, h1, ROWS, DM, DM);
  k_ln<1><<<dim3(ROWS), blk, 0, stream>>>(h1, g1, be1, x1f, x1b);

  k_gemm_bt<1><<<dim3(FF / 128, ROWS / 128), blk, 0, stream>>>(
      x1b, w1b, b1, nullptr, t1b, nullptr, ROWS, FF, DM);
  float* z = h1;
  k_gemm_bt<2><<<dim3(DM / 128, ROWS / 128), blk, 0, stream>>>(
      t1b, w2b, b2, x1f, nullptr, z, ROWS, DM, FF);
  k_ln<0><<<dim3(ROWS), blk, 0, stream>>>(z, g2, be2, (float*)d_out, nullptr);
}

// Round 3
// 304.770 us; speedup vs baseline: 1.5831x; 1.2879x over previous
//
#include <hip/hip_runtime.h>

// CausalSALayer: post-norm transformer decoder layer on gfx950.
// B=2, N=2048, D=1024, H=16, dk=64, FFN=4096. bf16 MFMA compute, f32 accum.

#define DEV __device__ __forceinline__

typedef __attribute__((ext_vector_type(4)))  float f32x4;
typedef __attribute__((ext_vector_type(16))) float f32x16;
typedef __attribute__((ext_vector_type(8)))  short s16x8;

static constexpr int Bb   = 2;
static constexpr int NN   = 2048;
static constexpr int DM   = 1024;
static constexpr int HH   = 16;
static constexpr int DK   = 64;
static constexpr int FF   = 4096;
static constexpr int ROWS = Bb * NN;  // 4096

#define AS1(p) ((const __attribute__((address_space(1))) void*)(p))
#define AS3(p) ((__attribute__((address_space(3))) void*)(p))

DEV unsigned short f2bf(float f) {
  unsigned u = __float_as_uint(f);
  u += 0x7fff + ((u >> 16) & 1);   // RNE
  return (unsigned short)(u >> 16);
}
DEV unsigned pack2bf(float lo, float hi) {
  return (unsigned)f2bf(lo) | ((unsigned)f2bf(hi) << 16);
}

// ---------------- cast f32 -> bf16 (vectorized) ----------------
__global__ __launch_bounds__(256) void k_cast(const float* __restrict__ in,
                                              ushort* __restrict__ out, int n4) {
  int i = blockIdx.x * 256 + threadIdx.x;
  if (i >= n4) return;
  float4 v = reinterpret_cast<const float4*>(in)[i];
  ushort4 o;
  o.x = f2bf(v.x); o.y = f2bf(v.y); o.z = f2bf(v.z); o.w = f2bf(v.w);
  reinterpret_cast<ushort4*>(out)[i] = o;
}

// ---------------- GEMM: C[128-rows x BN-cols blocks] = A[M,K] * Bt[NB,K]^T ----------
// 2-phase prefetch: stage(t+1) issued BEFORE compute(t); one barrier per K-step.
// EPI 0: C -> bf16 ; EPI 1: C+bias, fast gelu -> bf16 ; EPI 2: C+bias+resid -> f32
// QKV: Bt is virtual [3*DM][K] (contig wq,wk,wv); output routed to 3 contig buffers.
template <int EPI, int BN, bool QKV>
__global__ __launch_bounds__(256) void k_gemm(
    const ushort* __restrict__ A, const ushort* __restrict__ Bt,
    const float* __restrict__ bias, const float* __restrict__ resid,
    ushort* __restrict__ Cb, float* __restrict__ Cf,
    int K, int nbx) {
  __shared__ ushort As[2][128][32];
  __shared__ ushort Bs[2][BN][32];

  const int t = threadIdx.x;
  const int lane = t & 63, w = t >> 6;
  const int lr = lane & 15, lg = lane >> 4;
  const int lrow = lane >> 2, lc8 = (lane & 3) * 8;

  // bijective XCD chunking (m204) + group-of-4-rows decode
  const int nwg = gridDim.x;
  const int bid = blockIdx.x;
  const int q8 = nwg >> 3, r8 = nwg & 7;
  const int xcd = bid & 7, lin = bid >> 3;
  const int wg = (xcd < r8 ? xcd * (q8 + 1) : r8 * (q8 + 1) + (xcd - r8) * q8) + lin;
  const int band = wg / (4 * nbx);
  const int inn  = wg % (4 * nbx);
  const int by = band * 4 + (inn & 3);
  const int bx = inn >> 2;

  const int bRow = by * 128;
  const int bCol = bx * BN;

  constexpr int NW = BN / 32;
  const int wRow = (w >> 1) * 64, wCol = (w & 1) * (BN / 2);

  const f32x4 zero = {0.f, 0.f, 0.f, 0.f};
  f32x4 acc[4][NW];
#pragma unroll
  for (int m = 0; m < 4; ++m)
#pragma unroll
    for (int n = 0; n < NW; ++n) acc[m][n] = zero;

  auto stage = [&](int buf, int kt) {
#pragma unroll
    for (int i = 0; i < 2; ++i) {
      int rr = w * 32 + i * 16;
      __builtin_amdgcn_global_load_lds(
          AS1(A + (size_t)(bRow + rr + lrow) * K + kt + lc8),
          AS3(&As[buf][rr][0]), 16, 0, 0);
    }
#pragma unroll
    for (int i = 0; i < BN / 64; ++i) {
      int rr = w * (BN / 4) + i * 16;
      __builtin_amdgcn_global_load_lds(
          AS1(Bt + (size_t)(bCol + rr + lrow) * K + kt + lc8),
          AS3(&Bs[buf][rr][0]), 16, 0, 0);
    }
  };

  stage(0, 0);
  const int nk = K / 32;
  for (int tt = 0; tt < nk; ++tt) {
    const int cur = tt & 1;
    __syncthreads();                 // drains stage(tt) + prior tile's LDS reads
    if (tt + 1 < nk) stage(cur ^ 1, (tt + 1) * 32);

    s16x8 af[4], bfr[NW];
#pragma unroll
    for (int m = 0; m < 4; ++m)
      af[m] = *reinterpret_cast<const s16x8*>(&As[cur][wRow + m * 16 + lr][lg * 8]);
#pragma unroll
    for (int n = 0; n < NW; ++n)
      bfr[n] = *reinterpret_cast<const s16x8*>(&Bs[cur][wCol + n * 16 + lr][lg * 8]);
#pragma unroll
    for (int m = 0; m < 4; ++m)
#pragma unroll
      for (int n = 0; n < NW; ++n)
        acc[m][n] = __builtin_amdgcn_mfma_f32_16x16x32_bf16(af[m], bfr[n], acc[m][n], 0, 0, 0);
  }

  // ---- epilogue ----
  ushort* CbOut = Cb;
  int colBase = bCol, Ncols = nbx * BN;
  if (QKV) {
    CbOut = Cb + (size_t)(bCol >> 10) * ROWS * DM;
    colBase = bCol & 1023;
    Ncols = DM;
  }
#pragma unroll
  for (int m = 0; m < 4; ++m) {
    int gr = bRow + wRow + m * 16 + lg * 4;
#pragma unroll
    for (int n = 0; n < NW; ++n) {
      int gc = colBase + wCol + n * 16 + lr;
      float bv = (EPI == 1 || EPI == 2) ? bias[gc] : 0.0f;
#pragma unroll
      for (int r = 0; r < 4; ++r) {
        size_t idx = (size_t)(gr + r) * Ncols + gc;
        float v = acc[m][n][r] + bv;
        if (EPI == 2) {
          Cf[idx] = v + resid[idx];
        } else if (EPI == 1) {
          // tanh-gelu, sigmoid form: v * sigmoid(2*0.79788456*(v+0.044715 v^3))
          float u = v + 0.044715f * v * v * v;
          float g = v / (1.0f + __expf(-1.5957691216057308f * u));
          CbOut[idx] = f2bf(g);
        } else {
          CbOut[idx] = f2bf(v);
        }
      }
    }
  }
}

// ---------------- LayerNorm over D=1024 rows ----------------
template <int WB>
__global__ __launch_bounds__(256) void k_ln(const float* __restrict__ in,
                                            const float* __restrict__ g,
                                            const float* __restrict__ bta,
                                            float* __restrict__ outf,
                                            ushort* __restrict__ outb) {
  const int row = blockIdx.x;
  const int t = threadIdx.x;
  float4 v = reinterpret_cast<const float4*>(in + (size_t)row * DM)[t];
  float s1 = v.x + v.y + v.z + v.w;
  float s2 = v.x * v.x + v.y * v.y + v.z * v.z + v.w * v.w;
#pragma unroll
  for (int m = 32; m; m >>= 1) {
    s1 += __shfl_xor(s1, m, 64);
    s2 += __shfl_xor(s2, m, 64);
  }
  __shared__ float red[2][4];
  if ((t & 63) == 0) { red[0][t >> 6] = s1; red[1][t >> 6] = s2; }
  __syncthreads();
  s1 = red[0][0] + red[0][1] + red[0][2] + red[0][3];
  s2 = red[1][0] + red[1][1] + red[1][2] + red[1][3];
  const float mu = s1 * (1.0f / DM);
  const float var = s2 * (1.0f / DM) - mu * mu;
  const float rstd = rsqrtf(var + 1e-5f);
  float4 gv = reinterpret_cast<const float4*>(g)[t];
  float4 bv = reinterpret_cast<const float4*>(bta)[t];
  float4 o;
  o.x = (v.x - mu) * rstd * gv.x + bv.x;
  o.y = (v.y - mu) * rstd * gv.y + bv.y;
  o.z = (v.z - mu) * rstd * gv.z + bv.z;
  o.w = (v.w - mu) * rstd * gv.w + bv.w;
  reinterpret_cast<float4*>(outf + (size_t)row * DM)[t] = o;
  if (WB) {
    ushort4 ob;
    ob.x = f2bf(o.x); ob.y = f2bf(o.y); ob.z = f2bf(o.z); ob.w = f2bf(o.w);
    reinterpret_cast<ushort4*>(outb + (size_t)row * DM)[t] = ob;
  }
}

// ---------------- causal flash attention: swapped-operand 32x32 ----------------
__global__ __launch_bounds__(256) void k_attn(const ushort* __restrict__ Q,
                                              const ushort* __restrict__ Kb,
                                              const ushort* __restrict__ Vb,
                                              ushort* __restrict__ O) {
  __shared__ ushort Ks[64 * 64];   // byte-addressed, XOR-swizzled rows of 128B
  __shared__ ushort Vt[64][72];    // V^T [d][key], +8 pad

  const int t = threadIdx.x;
  const int qi = (NN / 128 - 1) - (int)blockIdx.x;   // heavy blocks first
  const int bh = blockIdx.y;
  const int b = bh >> 4, h = bh & 15;
  const int lane = t & 63, wid = t >> 6;
  const int l31 = lane & 31, hi = lane >> 5;
  const int q0w = qi * 128 + wid * 32;
  const size_t base = ((size_t)b * NN) * DM + h * DK;

  char* KsB = (char*)Ks;

  s16x8 qf[4];
#pragma unroll
  for (int c = 0; c < 4; ++c)
    qf[c] = *reinterpret_cast<const s16x8*>(Q + base + (size_t)(q0w + l31) * DM + c * 16 + hi * 8);

  float mrun = -1e30f, lrun = 0.f;
  f32x16 accO[2];
#pragma unroll
  for (int dt = 0; dt < 2; ++dt)
#pragma unroll
    for (int r = 0; r < 16; ++r) accO[dt][r] = 0.f;

  const int srow = t >> 2;
  const int sc4  = t & 3;

  const int nkt = 2 * qi + 2;
  for (int kt = 0; kt < nkt; ++kt) {
    const int kk = kt * 64;
#pragma unroll
    for (int hh = 0; hh < 2; ++hh) {
      int co = sc4 * 16 + hh * 64;
      int4 kv = *reinterpret_cast<const int4*>(Kb + base + (size_t)(kk + srow) * DM + (co >> 1));
      *reinterpret_cast<int4*>(KsB + srow * 128 + (co ^ ((srow & 7) << 4))) = kv;
      int d0 = sc4 * 8 + hh * 32;
      int4 vv = *reinterpret_cast<const int4*>(Vb + base + (size_t)(kk + srow) * DM + d0);
      ushort vs[8];
      *reinterpret_cast<int4*>(vs) = vv;
#pragma unroll
      for (int j = 0; j < 8; ++j) Vt[d0 + j][srow] = vs[j];
    }
    __syncthreads();

    if (kk <= q0w + 31) {
      f32x16 st[2];
#pragma unroll
      for (int sub = 0; sub < 2; ++sub) {
#pragma unroll
        for (int r = 0; r < 16; ++r) st[sub][r] = 0.f;
        const int row = sub * 32 + l31;
        const int swz = (row & 7) << 4;
#pragma unroll
        for (int c = 0; c < 4; ++c) {
          s16x8 kf = *reinterpret_cast<const s16x8*>(KsB + row * 128 + ((c * 32 + hi * 16) ^ swz));
          st[sub] = __builtin_amdgcn_mfma_f32_32x32x16_bf16(kf, qf[c], st[sub], 0, 0, 0);
        }
      }

      const int q = q0w + l31;
      const bool needmask = (kk + 63 > q0w);
      float p[32];
      float rm = -1e30f;
#pragma unroll
      for (int sub = 0; sub < 2; ++sub)
#pragma unroll
        for (int r = 0; r < 16; ++r) {
          int kl = sub * 32 + (r & 3) + 8 * (r >> 2) + 4 * hi;
          float v = st[sub][r] * 0.125f;
          if (needmask && (kk + kl > q)) v = -1e30f;
          p[sub * 16 + r] = v;
          rm = fmaxf(rm, v);
        }
      rm = fmaxf(rm, __shfl_xor(rm, 32, 64));
      const float mn = fmaxf(mrun, rm);
      const float alpha = __expf(mrun - mn);
      mrun = mn;
      float rs = 0.f;
#pragma unroll
      for (int i = 0; i < 32; ++i) { p[i] = __expf(p[i] - mn); rs += p[i]; }
      rs += __shfl_xor(rs, 32, 64);
      lrun = lrun * alpha + rs;
#pragma unroll
      for (int dt = 0; dt < 2; ++dt) accO[dt] *= alpha;

      s16x8 pf[4];
#pragma unroll
      for (int sub = 0; sub < 2; ++sub)
#pragma unroll
        for (int half = 0; half < 2; ++half) {
          const float* pp = &p[sub * 16 + half * 8];
          unsigned X0 = pack2bf(pp[0], pp[1]);
          unsigned X1 = pack2bf(pp[2], pp[3]);
          unsigned Y0 = pack2bf(pp[4], pp[5]);
          unsigned Y1 = pack2bf(pp[6], pp[7]);
          asm volatile("v_permlane32_swap_b32 %0, %1" : "+v"(X0), "+v"(Y0));
          asm volatile("v_permlane32_swap_b32 %0, %1" : "+v"(X1), "+v"(Y1));
          union { unsigned u[4]; s16x8 v; } uu;
          uu.u[0] = X0; uu.u[1] = X1; uu.u[2] = Y0; uu.u[3] = Y1;
          pf[sub * 2 + half] = uu.v;
        }

#pragma unroll
      for (int dt = 0; dt < 2; ++dt) {
        const int d = dt * 32 + l31;
#pragma unroll
        for (int kc = 0; kc < 4; ++kc) {
          s16x8 vf = *reinterpret_cast<const s16x8*>(&Vt[d][kc * 16 + hi * 8]);
          accO[dt] = __builtin_amdgcn_mfma_f32_32x32x16_bf16(vf, pf[kc], accO[dt], 0, 0, 0);
        }
      }
    }
    __syncthreads();
  }

  const int q = q0w + l31;
  const float inv = 1.0f / lrun;
#pragma unroll
  for (int dt = 0; dt < 2; ++dt)
#pragma unroll
    for (int rg = 0; rg < 4; ++rg) {
      int d0 = 8 * rg + 4 * hi + 32 * dt;
      ushort4 ov;
      ov.x = f2bf(accO[dt][rg * 4 + 0] * inv);
      ov.y = f2bf(accO[dt][rg * 4 + 1] * inv);
      ov.z = f2bf(accO[dt][rg * 4 + 2] * inv);
      ov.w = f2bf(accO[dt][rg * 4 + 3] * inv);
      *reinterpret_cast<ushort4*>(O + base + (size_t)q * DM + d0) = ov;
    }
}

// ---------------- launch ----------------
extern "C" void kernel_launch(void* const* d_in, const int* in_sizes, int n_in,
                              void* d_out, int out_size, void* d_ws, size_t ws_size,
                              hipStream_t stream) {
  const float* tgt = (const float*)d_in[0];
  const float* Wq  = (const float*)d_in[3];
  const float* Wk  = (const float*)d_in[4];
  const float* Wv  = (const float*)d_in[5];
  const float* Wo  = (const float*)d_in[6];
  const float* bo  = (const float*)d_in[7];
  const float* W1  = (const float*)d_in[8];
  const float* b1  = (const float*)d_in[9];
  const float* W2  = (const float*)d_in[10];
  const float* b2  = (const float*)d_in[11];
  const float* g1  = (const float*)d_in[12];
  const float* be1 = (const float*)d_in[13];
  const float* g2  = (const float*)d_in[14];
  const float* be2 = (const float*)d_in[15];

  char* ws = (char*)d_ws;
  size_t off = 0;
  auto alloc = [&](size_t bytes) {
    void* p = ws + off;
    off += (bytes + 255) & ~(size_t)255;
    return p;
  };
  // NOTE: wqb/wkb/wvb contiguous (virtual [3*DM][DM]); qbuf/kbuf/vbuf contiguous.
  ushort* xb   = (ushort*)alloc((size_t)ROWS * DM * 2);
  ushort* wqb  = (ushort*)alloc((size_t)DM * DM * 2);
  ushort* wkb  = (ushort*)alloc((size_t)DM * DM * 2);
  ushort* wvb  = (ushort*)alloc((size_t)DM * DM * 2);
  ushort* wob  = (ushort*)alloc((size_t)DM * DM * 2);
  ushort* w1b  = (ushort*)alloc((size_t)FF * DM * 2);
  ushort* w2b  = (ushort*)alloc((size_t)DM * FF * 2);
  ushort* qbuf = (ushort*)alloc((size_t)ROWS * DM * 2);
  ushort* kbuf = (ushort*)alloc((size_t)ROWS * DM * 2);
  ushort* vbuf = (ushort*)alloc((size_t)ROWS * DM * 2);
  ushort* atnb = (ushort*)alloc((size_t)ROWS * DM * 2);
  float*  h1   = (float*)alloc((size_t)ROWS * DM * 4);    // reused as z
  float*  x1f  = (float*)alloc((size_t)ROWS * DM * 4);
  ushort* x1b  = (ushort*)alloc((size_t)ROWS * DM * 2);
  ushort* t1b  = (ushort*)alloc((size_t)ROWS * FF * 2);
  (void)ws_size; (void)in_sizes; (void)n_in; (void)out_size;
  (void)wkb; (void)wvb; (void)kbuf; (void)vbuf;

  auto cast = [&](const float* src, ushort* dst, size_t n) {
    int n4 = (int)(n / 4);
    k_cast<<<dim3((n4 + 255) / 256), 256, 0, stream>>>(src, dst, n4);
  };
  cast(tgt, xb, (size_t)ROWS * DM);
  cast(Wq, wqb, (size_t)DM * DM);
  cast(Wk, wkb, (size_t)DM * DM);
  cast(Wv, wvb, (size_t)DM * DM);
  cast(Wo, wob, (size_t)DM * DM);
  cast(W1, w1b, (size_t)FF * DM);
  cast(W2, w2b, (size_t)DM * FF);

  dim3 blk(256);
  // fused QKV: virtual Bt [3072][1024], outputs routed into qbuf/kbuf/vbuf
  k_gemm<0, 128, true><<<dim3(24 * 32), blk, 0, stream>>>(
      xb, wqb, nullptr, nullptr, qbuf, nullptr, DM, 24);

  k_attn<<<dim3(NN / 128, Bb * HH), blk, 0, stream>>>(qbuf, kbuf, vbuf, atnb);

  // O-projection + bo + residual(tgt) -> f32 h1
  k_gemm<2, 64, false><<<dim3(16 * 32), blk, 0, stream>>>(
      atnb, wob, bo, tgt, nullptr, h1, DM, 16);
  k_ln<1><<<dim3(ROWS), blk, 0, stream>>>(h1, g1, be1, x1f, x1b);

  // FFN
  k_gemm<1, 128, false><<<dim3(32 * 32), blk, 0, stream>>>(
      x1b, w1b, b1, nullptr, t1b, nullptr, DM, 32);
  float* z = h1;
  k_gemm<2, 64, false><<<dim3(16 * 32), blk, 0, stream>>>(
      t1b, w2b, b2, x1f, nullptr, z, FF, 16);
  k_ln<0><<<dim3(ROWS), blk, 0, stream>>>(z, g2, be2, (float*)d_out, nullptr);
}